// Round 1
// baseline (2898.202 us; speedup 1.0000x reference)
//
#include <hip/hip_runtime.h>

#define D 64
#define THREADS 256

// ---- degree: deg[dst[e]] += w[e] ----
__global__ void deg_kernel(const float* __restrict__ w, const int* __restrict__ dst,
                           float* __restrict__ deg, int E) {
    int e = blockIdx.x * blockDim.x + threadIdx.x;
    if (e < E) unsafeAtomicAdd(&deg[dst[e]], w[e]);
}

// ---- norm[i] = 1/sqrt(max(deg,1)) ----
__global__ void norm_kernel(const float* __restrict__ deg, float* __restrict__ norm, int N) {
    int i = blockIdx.x * blockDim.x + threadIdx.x;
    if (i < N) norm[i] = 1.0f / sqrtf(fmaxf(deg[i], 1.0f));
}

// ---- scatter: acc[dst[e]][:] += cur[src[e]][:] * (w[e]*norm[src[e]]) ----
// 16 lanes per edge, each lane handles 4 contiguous dims via float4 gather + 4 atomics.
__global__ void scatter_kernel(const float* __restrict__ cur, const float* __restrict__ w,
                               const int* __restrict__ src, const int* __restrict__ dst,
                               const float* __restrict__ norm, float* __restrict__ acc, int E) {
    long long tid = (long long)blockIdx.x * blockDim.x + threadIdx.x;
    int e = (int)(tid >> 4);
    if (e >= E) return;
    int c = (int)(tid & 15);
    int s = src[e];
    int d = dst[e];
    float coef = w[e] * norm[s];
    const float4 v = ((const float4*)(cur + (long long)s * D))[c];
    float* o = acc + (long long)d * D + c * 4;
    unsafeAtomicAdd(o + 0, v.x * coef);
    unsafeAtomicAdd(o + 1, v.y * coef);
    unsafeAtomicAdd(o + 2, v.z * coef);
    unsafeAtomicAdd(o + 3, v.w * coef);
}

// ---- scale: out[i][:] = acc[i][:] * norm[i] ----  (N*16 threads, float4 each)
__global__ void scale_kernel(const float* __restrict__ acc, const float* __restrict__ norm,
                             float* __restrict__ out, int N) {
    int tid = blockIdx.x * blockDim.x + threadIdx.x;
    if (tid >= N * 16) return;
    int i = tid >> 4, c = tid & 15;
    float nv = norm[i];
    float4 v = ((const float4*)(acc + (long long)i * D))[c];
    v.x *= nv; v.y *= nv; v.z *= nv; v.w *= nv;
    ((float4*)(out + (long long)i * D))[c] = v;
}

// ---- final: out[i][:] = (h[i][:] + h1[i][:] (already in out) + acc[i][:]*norm[i]) / 3 ----
__global__ void final_kernel(const float* __restrict__ h, const float* __restrict__ acc,
                             const float* __restrict__ norm, float* __restrict__ out, int N) {
    int tid = blockIdx.x * blockDim.x + threadIdx.x;
    if (tid >= N * 16) return;
    int i = tid >> 4, c = tid & 15;
    float nv = norm[i];
    float4 a = ((const float4*)(h   + (long long)i * D))[c];
    float4 b = ((float4*)(out       + (long long)i * D))[c];   // h1 lives in out
    float4 g = ((const float4*)(acc + (long long)i * D))[c];
    const float inv3 = 1.0f / 3.0f;
    float4 r;
    r.x = (a.x + b.x + g.x * nv) * inv3;
    r.y = (a.y + b.y + g.y * nv) * inv3;
    r.z = (a.z + b.z + g.z * nv) * inv3;
    r.w = (a.w + b.w + g.w * nv) * inv3;
    ((float4*)(out + (long long)i * D))[c] = r;
}

extern "C" void kernel_launch(void* const* d_in, const int* in_sizes, int n_in,
                              void* d_out, int out_size, void* d_ws, size_t ws_size,
                              hipStream_t stream) {
    const float* h   = (const float*)d_in[0];
    const float* w   = (const float*)d_in[1];
    const int*   src = (const int*)d_in[2];
    const int*   dst = (const int*)d_in[3];
    const int N = in_sizes[0] / D;   // 100000
    const int E = in_sizes[1];       // 1600000
    float* out = (float*)d_out;

    float* deg  = (float*)d_ws;                     // N
    float* norm = deg + N;                          // N
    float* acc  = norm + N;                         // N*D  (offset 800000 B, 16B-aligned)

    // degree + norm
    hipMemsetAsync(deg, 0, (size_t)N * sizeof(float), stream);
    deg_kernel<<<(E + THREADS - 1) / THREADS, THREADS, 0, stream>>>(w, dst, deg, E);
    norm_kernel<<<(N + THREADS - 1) / THREADS, THREADS, 0, stream>>>(deg, norm, N);

    const long long scatter_threads = (long long)E * 16;
    const int scatter_blocks = (int)((scatter_threads + THREADS - 1) / THREADS);
    const int node_threads = N * 16;
    const int node_blocks = (node_threads + THREADS - 1) / THREADS;

    // layer 1: h -> acc -> h1 (stored in out)
    hipMemsetAsync(acc, 0, (size_t)N * D * sizeof(float), stream);
    scatter_kernel<<<scatter_blocks, THREADS, 0, stream>>>(h, w, src, dst, norm, acc, E);
    scale_kernel<<<node_blocks, THREADS, 0, stream>>>(acc, norm, out, N);

    // layer 2: h1 (in out) -> acc; epilogue fuses h2 = acc*norm and the mean
    hipMemsetAsync(acc, 0, (size_t)N * D * sizeof(float), stream);
    scatter_kernel<<<scatter_blocks, THREADS, 0, stream>>>(out, w, src, dst, norm, acc, E);
    final_kernel<<<node_blocks, THREADS, 0, stream>>>(h, acc, norm, out, N);
}

// Round 2
// 563.261 us; speedup vs baseline: 5.1454x; 5.1454x over previous
//
#include <hip/hip_runtime.h>

#define D 64
#define THREADS 256
#define SCAN_BLOCK 256

// ---- pass 1 over edges: weighted degree + integer in-degree histogram ----
__global__ void deg_count_kernel(const float* __restrict__ w, const int* __restrict__ dst,
                                 float* __restrict__ deg, int* __restrict__ cnt, int E) {
    int e = blockIdx.x * blockDim.x + threadIdx.x;
    if (e < E) {
        int d = dst[e];
        unsafeAtomicAdd(&deg[d], w[e]);
        atomicAdd(&cnt[d], 1);
    }
}

// ---- norm[i] = 1/sqrt(max(deg,1)) ----
__global__ void norm_kernel(const float* __restrict__ deg, float* __restrict__ norm, int N) {
    int i = blockIdx.x * blockDim.x + threadIdx.x;
    if (i < N) norm[i] = 1.0f / sqrtf(fmaxf(deg[i], 1.0f));
}

// ---- scan step A: per-block sums of cnt ----
__global__ void blocksum_kernel(const int* __restrict__ cnt, int* __restrict__ partial, int N) {
    __shared__ int sm[SCAN_BLOCK];
    int i = blockIdx.x * SCAN_BLOCK + threadIdx.x;
    sm[threadIdx.x] = (i < N) ? cnt[i] : 0;
    __syncthreads();
    for (int s = SCAN_BLOCK / 2; s > 0; s >>= 1) {
        if (threadIdx.x < s) sm[threadIdx.x] += sm[threadIdx.x + s];
        __syncthreads();
    }
    if (threadIdx.x == 0) partial[blockIdx.x] = sm[0];
}

// ---- scan step B: exclusive scan of partials (single block, P <= 1024) ----
__global__ void scanpartials_kernel(int* __restrict__ partial, int P, int* __restrict__ rowptr,
                                    int N, int E) {
    __shared__ int sm[1024];
    int t = threadIdx.x;
    sm[t] = (t < P) ? partial[t] : 0;
    __syncthreads();
    // Hillis-Steele inclusive
    for (int off = 1; off < 1024; off <<= 1) {
        int v = (t >= off) ? sm[t - off] : 0;
        __syncthreads();
        sm[t] += v;
        __syncthreads();
    }
    if (t < P) partial[t] = (t == 0) ? 0 : sm[t - 1];  // exclusive
    if (t == 0) rowptr[N] = E;
}

// ---- scan step C: rowptr[i] = partial[b] + exclusive_scan_within_block; cursor=rowptr ----
__global__ void rowptr_kernel(const int* __restrict__ cnt, const int* __restrict__ partial,
                              int* __restrict__ rowptr, int* __restrict__ cursor, int N) {
    __shared__ int sm[SCAN_BLOCK];
    int i = blockIdx.x * SCAN_BLOCK + threadIdx.x;
    int v = (i < N) ? cnt[i] : 0;
    sm[threadIdx.x] = v;
    __syncthreads();
    // Hillis-Steele inclusive
    for (int off = 1; off < SCAN_BLOCK; off <<= 1) {
        int u = (threadIdx.x >= off) ? sm[threadIdx.x - off] : 0;
        __syncthreads();
        sm[threadIdx.x] += u;
        __syncthreads();
    }
    if (i < N) {
        int excl = sm[threadIdx.x] - v;
        int r = partial[blockIdx.x] + excl;
        rowptr[i] = r;
        cursor[i] = r;
    }
}

// ---- bucket fill: packed[pos] = (src, w*norm[src]) ----
__global__ void fill_kernel(const float* __restrict__ w, const int* __restrict__ src,
                            const int* __restrict__ dst, const float* __restrict__ norm,
                            int* __restrict__ cursor, int2* __restrict__ packed, int E) {
    int e = blockIdx.x * blockDim.x + threadIdx.x;
    if (e < E) {
        int d = dst[e];
        int s = src[e];
        int pos = atomicAdd(&cursor[d], 1);
        float c = w[e] * norm[s];
        packed[pos] = make_int2(s, __float_as_int(c));
    }
}

// ---- gather layer 1: h1[i] = norm[i] * sum_{e in in(i)} h[src_e] * coef_e ----
// one wave (64 lanes) per node, lane = dim
__global__ void gather1_kernel(const float* __restrict__ h_in, const int2* __restrict__ packed,
                               const int* __restrict__ rowptr, const float* __restrict__ norm,
                               float* __restrict__ h_out, int N) {
    int node = blockIdx.x * (blockDim.x >> 6) + (threadIdx.x >> 6);
    int lane = threadIdx.x & 63;
    if (node >= N) return;
    int j = rowptr[node];
    int end = rowptr[node + 1];
    float acc = 0.0f;
    int2 p = (j < end) ? packed[j] : make_int2(0, 0);
    while (j < end) {
        int2 pn = (j + 1 < end) ? packed[j + 1] : make_int2(0, 0);  // prefetch next meta
        float c = __int_as_float(p.y);
        acc = fmaf(h_in[(long long)p.x * D + lane], c, acc);
        p = pn;
        ++j;
    }
    h_out[(long long)node * D + lane] = acc * norm[node];
}

// ---- gather layer 2 fused with mean: out[i] = (h0[i] + h1[i] + norm[i]*sum h1[src]*coef)/3 ----
__global__ void gather2_final_kernel(const float* __restrict__ h0, const float* __restrict__ h1,
                                     const int2* __restrict__ packed, const int* __restrict__ rowptr,
                                     const float* __restrict__ norm, float* __restrict__ out, int N) {
    int node = blockIdx.x * (blockDim.x >> 6) + (threadIdx.x >> 6);
    int lane = threadIdx.x & 63;
    if (node >= N) return;
    int j = rowptr[node];
    int end = rowptr[node + 1];
    float acc = 0.0f;
    int2 p = (j < end) ? packed[j] : make_int2(0, 0);
    while (j < end) {
        int2 pn = (j + 1 < end) ? packed[j + 1] : make_int2(0, 0);
        float c = __int_as_float(p.y);
        acc = fmaf(h1[(long long)p.x * D + lane], c, acc);
        p = pn;
        ++j;
    }
    long long idx = (long long)node * D + lane;
    float h2 = acc * norm[node];
    out[idx] = (h0[idx] + h1[idx] + h2) * (1.0f / 3.0f);
}

extern "C" void kernel_launch(void* const* d_in, const int* in_sizes, int n_in,
                              void* d_out, int out_size, void* d_ws, size_t ws_size,
                              hipStream_t stream) {
    const float* h   = (const float*)d_in[0];
    const float* w   = (const float*)d_in[1];
    const int*   src = (const int*)d_in[2];
    const int*   dst = (const int*)d_in[3];
    const int N = in_sizes[0] / D;   // 100000
    const int E = in_sizes[1];       // 1600000
    float* out = (float*)d_out;

    // ---- workspace layout (4-byte elements; packed needs 8B alignment) ----
    char* ws = (char*)d_ws;
    size_t off = 0;
    auto alloc = [&](size_t bytes, size_t align) -> char* {
        off = (off + align - 1) & ~(align - 1);
        char* p = ws + off;
        off += bytes;
        return p;
    };
    float* deg    = (float*)alloc((size_t)N * 4, 4);
    float* norm   = (float*)alloc((size_t)N * 4, 4);
    int*   cnt    = (int*)  alloc((size_t)N * 4, 4);
    int*   rowptr = (int*)  alloc((size_t)(N + 1) * 4, 4);
    int*   cursor = (int*)  alloc((size_t)N * 4, 4);
    int*   partial= (int*)  alloc((size_t)1024 * 4, 4);
    int2*  packed = (int2*) alloc((size_t)E * 8, 8);
    float* h1     = (float*)alloc((size_t)N * D * 4, 16);

    const int eblocks = (E + THREADS - 1) / THREADS;
    const int nblocks = (N + THREADS - 1) / THREADS;
    const int P = (N + SCAN_BLOCK - 1) / SCAN_BLOCK;   // 391 <= 1024
    const int gather_blocks = (N * 64 + THREADS - 1) / THREADS;

    // zero deg + cnt
    hipMemsetAsync(deg, 0, (size_t)N * 4, stream);
    hipMemsetAsync(cnt, 0, (size_t)N * 4, stream);

    // build norm + CSR
    deg_count_kernel<<<eblocks, THREADS, 0, stream>>>(w, dst, deg, cnt, E);
    norm_kernel<<<nblocks, THREADS, 0, stream>>>(deg, norm, N);
    blocksum_kernel<<<P, SCAN_BLOCK, 0, stream>>>(cnt, partial, N);
    scanpartials_kernel<<<1, 1024, 0, stream>>>(partial, P, rowptr, N, E);
    rowptr_kernel<<<P, SCAN_BLOCK, 0, stream>>>(cnt, partial, rowptr, cursor, N);
    fill_kernel<<<eblocks, THREADS, 0, stream>>>(w, src, dst, norm, cursor, packed, E);

    // layer 1: h -> h1 (in ws)
    gather1_kernel<<<gather_blocks, THREADS, 0, stream>>>(h, packed, rowptr, norm, h1, N);
    // layer 2 + epilogue: out = (h + h1 + h2)/3
    gather2_final_kernel<<<gather_blocks, THREADS, 0, stream>>>(h, h1, packed, rowptr, norm, out, N);
}

// Round 3
// 401.856 us; speedup vs baseline: 7.2120x; 1.4017x over previous
//
#include <hip/hip_runtime.h>

#define D 64
#define THREADS 256
#define SCAN_BLOCK 256

// ---- pass 1: in-degree histogram + within-row rank (THE only atomic pass) ----
__global__ void count_rank_kernel(const int* __restrict__ dst, int* __restrict__ cnt,
                                  int* __restrict__ rank, int E) {
    int e = blockIdx.x * blockDim.x + threadIdx.x;
    if (e < E) rank[e] = atomicAdd(&cnt[dst[e]], 1);
}

// ---- scan step A: per-block sums of cnt ----
__global__ void blocksum_kernel(const int* __restrict__ cnt, int* __restrict__ partial, int N) {
    __shared__ int sm[SCAN_BLOCK];
    int i = blockIdx.x * SCAN_BLOCK + threadIdx.x;
    sm[threadIdx.x] = (i < N) ? cnt[i] : 0;
    __syncthreads();
    for (int s = SCAN_BLOCK / 2; s > 0; s >>= 1) {
        if (threadIdx.x < s) sm[threadIdx.x] += sm[threadIdx.x + s];
        __syncthreads();
    }
    if (threadIdx.x == 0) partial[blockIdx.x] = sm[0];
}

// ---- scan step B: exclusive scan of partials (single block, P <= 1024) ----
__global__ void scanpartials_kernel(int* __restrict__ partial, int P, int* __restrict__ rowptr,
                                    int N, int E) {
    __shared__ int sm[1024];
    int t = threadIdx.x;
    sm[t] = (t < P) ? partial[t] : 0;
    __syncthreads();
    for (int off = 1; off < 1024; off <<= 1) {
        int v = (t >= off) ? sm[t - off] : 0;
        __syncthreads();
        sm[t] += v;
        __syncthreads();
    }
    if (t < P) partial[t] = (t == 0) ? 0 : sm[t - 1];  // exclusive
    if (t == 0) rowptr[N] = E;
}

// ---- scan step C: rowptr[i] = partial[b] + exclusive_scan_within_block ----
__global__ void rowptr_kernel(const int* __restrict__ cnt, const int* __restrict__ partial,
                              int* __restrict__ rowptr, int N) {
    __shared__ int sm[SCAN_BLOCK];
    int i = blockIdx.x * SCAN_BLOCK + threadIdx.x;
    int v = (i < N) ? cnt[i] : 0;
    sm[threadIdx.x] = v;
    __syncthreads();
    for (int off = 1; off < SCAN_BLOCK; off <<= 1) {
        int u = (threadIdx.x >= off) ? sm[threadIdx.x - off] : 0;
        __syncthreads();
        sm[threadIdx.x] += u;
        __syncthreads();
    }
    if (i < N) rowptr[i] = partial[blockIdx.x] + (sm[threadIdx.x] - v);
}

// ---- fill: packed[rowptr[dst]+rank] = (src, w)   -- NO atomics ----
__global__ void fill_kernel(const float* __restrict__ w, const int* __restrict__ src,
                            const int* __restrict__ dst, const int* __restrict__ rank,
                            const int* __restrict__ rowptr, int2* __restrict__ packed, int E) {
    int e = blockIdx.x * blockDim.x + threadIdx.x;
    if (e < E) {
        int pos = rowptr[dst[e]] + rank[e];
        packed[pos] = make_int2(src[e], __float_as_int(w[e]));
    }
}

// ---- deg from CSR (segmented sum of w) fused with norm = rsqrt(max(deg,1)) ----
__global__ void degnorm_kernel(const int2* __restrict__ packed, const int* __restrict__ rowptr,
                               float* __restrict__ norm, int N) {
    int i = blockIdx.x * blockDim.x + threadIdx.x;
    if (i >= N) return;
    int j = rowptr[i], end = rowptr[i + 1];
    float s = 0.0f;
    for (; j < end; ++j) s += __int_as_float(packed[j].y);
    norm[i] = rsqrtf(fmaxf(s, 1.0f));
}

// ---- coef rewrite: packed[j].y = w * norm[src] ----
__global__ void coef_kernel(int2* __restrict__ packed, const float* __restrict__ norm, int E) {
    int j = blockIdx.x * blockDim.x + threadIdx.x;
    if (j < E) {
        int2 p = packed[j];
        p.y = __float_as_int(__int_as_float(p.y) * norm[p.x]);
        packed[j] = p;
    }
}

// ---- gather layer 1: h1[i] = norm[i] * sum h[src_e]*coef_e   (wave per node, lane=dim) ----
__global__ void gather1_kernel(const float* __restrict__ h_in, const int2* __restrict__ packed,
                               const int* __restrict__ rowptr, const float* __restrict__ norm,
                               float* __restrict__ h_out, int N) {
    int node = blockIdx.x * (blockDim.x >> 6) + (threadIdx.x >> 6);
    int lane = threadIdx.x & 63;
    if (node >= N) return;
    int j = rowptr[node], end = rowptr[node + 1];
    float acc0 = 0.0f, acc1 = 0.0f;
    for (; j + 2 <= end; j += 2) {
        int2 p0 = packed[j];
        int2 p1 = packed[j + 1];
        float v0 = h_in[(long long)p0.x * D + lane];
        float v1 = h_in[(long long)p1.x * D + lane];
        acc0 = fmaf(v0, __int_as_float(p0.y), acc0);
        acc1 = fmaf(v1, __int_as_float(p1.y), acc1);
    }
    if (j < end) {
        int2 p = packed[j];
        acc0 = fmaf(h_in[(long long)p.x * D + lane], __int_as_float(p.y), acc0);
    }
    h_out[(long long)node * D + lane] = (acc0 + acc1) * norm[node];
}

// ---- gather layer 2 fused with mean: out = (h0 + h1 + norm*sum h1[src]*coef)/3 ----
__global__ void gather2_final_kernel(const float* __restrict__ h0, const float* __restrict__ h1,
                                     const int2* __restrict__ packed, const int* __restrict__ rowptr,
                                     const float* __restrict__ norm, float* __restrict__ out, int N) {
    int node = blockIdx.x * (blockDim.x >> 6) + (threadIdx.x >> 6);
    int lane = threadIdx.x & 63;
    if (node >= N) return;
    int j = rowptr[node], end = rowptr[node + 1];
    float acc0 = 0.0f, acc1 = 0.0f;
    for (; j + 2 <= end; j += 2) {
        int2 p0 = packed[j];
        int2 p1 = packed[j + 1];
        float v0 = h1[(long long)p0.x * D + lane];
        float v1 = h1[(long long)p1.x * D + lane];
        acc0 = fmaf(v0, __int_as_float(p0.y), acc0);
        acc1 = fmaf(v1, __int_as_float(p1.y), acc1);
    }
    if (j < end) {
        int2 p = packed[j];
        acc0 = fmaf(h1[(long long)p.x * D + lane], __int_as_float(p.y), acc0);
    }
    long long idx = (long long)node * D + lane;
    float h2 = (acc0 + acc1) * norm[node];
    out[idx] = (h0[idx] + h1[idx] + h2) * (1.0f / 3.0f);
}

extern "C" void kernel_launch(void* const* d_in, const int* in_sizes, int n_in,
                              void* d_out, int out_size, void* d_ws, size_t ws_size,
                              hipStream_t stream) {
    const float* h   = (const float*)d_in[0];
    const float* w   = (const float*)d_in[1];
    const int*   src = (const int*)d_in[2];
    const int*   dst = (const int*)d_in[3];
    const int N = in_sizes[0] / D;   // 100000
    const int E = in_sizes[1];       // 1600000
    float* out = (float*)d_out;

    // ---- workspace layout ----
    char* ws = (char*)d_ws;
    size_t off = 0;
    auto alloc = [&](size_t bytes, size_t align) -> char* {
        off = (off + align - 1) & ~(align - 1);
        char* p = ws + off;
        off += bytes;
        return p;
    };
    float* norm   = (float*)alloc((size_t)N * 4, 4);
    int*   cnt    = (int*)  alloc((size_t)N * 4, 4);
    int*   rowptr = (int*)  alloc((size_t)(N + 1) * 4, 4);
    int*   partial= (int*)  alloc((size_t)1024 * 4, 4);
    int*   rank   = (int*)  alloc((size_t)E * 4, 4);
    int2*  packed = (int2*) alloc((size_t)E * 8, 8);
    float* h1     = (float*)alloc((size_t)N * D * 4, 16);

    const int eblocks = (E + THREADS - 1) / THREADS;
    const int nblocks = (N + THREADS - 1) / THREADS;
    const int P = (N + SCAN_BLOCK - 1) / SCAN_BLOCK;   // 391 <= 1024
    const int waves_per_block = THREADS / 64;
    const int gather_blocks = (N + waves_per_block - 1) / waves_per_block;

    hipMemsetAsync(cnt, 0, (size_t)N * 4, stream);

    // CSR build: 1 atomic per edge total
    count_rank_kernel<<<eblocks, THREADS, 0, stream>>>(dst, cnt, rank, E);
    blocksum_kernel<<<P, SCAN_BLOCK, 0, stream>>>(cnt, partial, N);
    scanpartials_kernel<<<1, 1024, 0, stream>>>(partial, P, rowptr, N, E);
    rowptr_kernel<<<P, SCAN_BLOCK, 0, stream>>>(cnt, partial, rowptr, N);
    fill_kernel<<<eblocks, THREADS, 0, stream>>>(w, src, dst, rank, rowptr, packed, E);

    // norm from CSR (no atomics), then fold norm[src] into edge coefs
    degnorm_kernel<<<nblocks, THREADS, 0, stream>>>(packed, rowptr, norm, N);
    coef_kernel<<<eblocks, THREADS, 0, stream>>>(packed, norm, E);

    // layer 1: h -> h1 (ws); layer 2 + mean epilogue -> out
    gather1_kernel<<<gather_blocks, THREADS, 0, stream>>>(h, packed, rowptr, norm, h1, N);
    gather2_final_kernel<<<gather_blocks, THREADS, 0, stream>>>(h, h1, packed, rowptr, norm, out, N);
}

// Round 4
// 360.759 us; speedup vs baseline: 8.0336x; 1.1139x over previous
//
#include <hip/hip_runtime.h>
#include <hip/hip_bf16.h>

#define D 64
#define THREADS 256
#define SCAN_BLOCK 256
#define CSTRIDE 32   // one int counter per 128B cache line

__device__ __forceinline__ float bf2f(unsigned short u) {
    return __uint_as_float(((unsigned)u) << 16);
}

// ---- pass 1: in-degree histogram (line-strided counters) + within-row rank ----
__global__ void count_rank_kernel(const int* __restrict__ dst, int* __restrict__ cntS,
                                  int* __restrict__ rank, int E) {
    int e = blockIdx.x * blockDim.x + threadIdx.x;
    if (e < E) rank[e] = atomicAdd(&cntS[(long long)dst[e] * CSTRIDE], 1);
}

// ---- scan step A: per-block sums of cnt ----
__global__ void blocksum_kernel(const int* __restrict__ cntS, int* __restrict__ partial, int N) {
    __shared__ int sm[SCAN_BLOCK];
    int i = blockIdx.x * SCAN_BLOCK + threadIdx.x;
    sm[threadIdx.x] = (i < N) ? cntS[(long long)i * CSTRIDE] : 0;
    __syncthreads();
    for (int s = SCAN_BLOCK / 2; s > 0; s >>= 1) {
        if (threadIdx.x < s) sm[threadIdx.x] += sm[threadIdx.x + s];
        __syncthreads();
    }
    if (threadIdx.x == 0) partial[blockIdx.x] = sm[0];
}

// ---- scan step B: exclusive scan of partials (single block, P <= 1024) ----
__global__ void scanpartials_kernel(int* __restrict__ partial, int P, int* __restrict__ rowptr,
                                    int N, int E) {
    __shared__ int sm[1024];
    int t = threadIdx.x;
    sm[t] = (t < P) ? partial[t] : 0;
    __syncthreads();
    for (int off = 1; off < 1024; off <<= 1) {
        int v = (t >= off) ? sm[t - off] : 0;
        __syncthreads();
        sm[t] += v;
        __syncthreads();
    }
    if (t < P) partial[t] = (t == 0) ? 0 : sm[t - 1];  // exclusive
    if (t == 0) rowptr[N] = E;
}

// ---- scan step C: rowptr[i] = partial[b] + exclusive_scan_within_block ----
__global__ void rowptr_kernel(const int* __restrict__ cntS, const int* __restrict__ partial,
                              int* __restrict__ rowptr, int N) {
    __shared__ int sm[SCAN_BLOCK];
    int i = blockIdx.x * SCAN_BLOCK + threadIdx.x;
    int v = (i < N) ? cntS[(long long)i * CSTRIDE] : 0;
    sm[threadIdx.x] = v;
    __syncthreads();
    for (int off = 1; off < SCAN_BLOCK; off <<= 1) {
        int u = (threadIdx.x >= off) ? sm[threadIdx.x - off] : 0;
        __syncthreads();
        sm[threadIdx.x] += u;
        __syncthreads();
    }
    if (i < N) rowptr[i] = partial[blockIdx.x] + (sm[threadIdx.x] - v);
}

// ---- fill: packed[rowptr[dst]+rank] = (src, w)   -- NO atomics ----
__global__ void fill_kernel(const float* __restrict__ w, const int* __restrict__ src,
                            const int* __restrict__ dst, const int* __restrict__ rank,
                            const int* __restrict__ rowptr, int2* __restrict__ packed, int E) {
    int e = blockIdx.x * blockDim.x + threadIdx.x;
    if (e < E) {
        int pos = rowptr[dst[e]] + rank[e];
        packed[pos] = make_int2(src[e], __float_as_int(w[e]));
    }
}

// ---- deg from CSR (segmented sum of w) fused with norm = rsqrt(max(deg,1)) ----
__global__ void degnorm_kernel(const int2* __restrict__ packed, const int* __restrict__ rowptr,
                               float* __restrict__ norm, int N) {
    int i = blockIdx.x * blockDim.x + threadIdx.x;
    if (i >= N) return;
    int j = rowptr[i], end = rowptr[i + 1];
    float s = 0.0f;
    for (; j < end; ++j) s += __int_as_float(packed[j].y);
    norm[i] = rsqrtf(fmaxf(s, 1.0f));
}

// ---- coef rewrite: packed[j].y = w * norm[src] ----
__global__ void coef_kernel(int2* __restrict__ packed, const float* __restrict__ norm, int E) {
    int j = blockIdx.x * blockDim.x + threadIdx.x;
    if (j < E) {
        int2 p = packed[j];
        p.y = __float_as_int(__int_as_float(p.y) * norm[p.x]);
        packed[j] = p;
    }
}

// ---- h (fp32) -> h0bf (bf16, RNE) ----
__global__ void tobf16_kernel(const float* __restrict__ h, __hip_bfloat16* __restrict__ hbf,
                              long long n) {
    long long i = (long long)blockIdx.x * blockDim.x + threadIdx.x;
    if (i < n) hbf[i] = __float2bfloat16(h[i]);
}

// ---- gather layer 1: h1bf[i] = bf16( norm[i] * sum h0bf[src_e]*coef_e ) ----
// one wave per node, lane = dim; 4x unrolled edge loop for MLP
__global__ void gather1_kernel(const unsigned short* __restrict__ h_in,
                               const int2* __restrict__ packed,
                               const int* __restrict__ rowptr, const float* __restrict__ norm,
                               __hip_bfloat16* __restrict__ h_out, int N) {
    int node = blockIdx.x * (blockDim.x >> 6) + (threadIdx.x >> 6);
    int lane = threadIdx.x & 63;
    if (node >= N) return;
    int j = rowptr[node], end = rowptr[node + 1];
    float acc0 = 0.0f, acc1 = 0.0f, acc2 = 0.0f, acc3 = 0.0f;
    for (; j + 4 <= end; j += 4) {
        int2 p0 = packed[j], p1 = packed[j + 1], p2 = packed[j + 2], p3 = packed[j + 3];
        float v0 = bf2f(h_in[(long long)p0.x * D + lane]);
        float v1 = bf2f(h_in[(long long)p1.x * D + lane]);
        float v2 = bf2f(h_in[(long long)p2.x * D + lane]);
        float v3 = bf2f(h_in[(long long)p3.x * D + lane]);
        acc0 = fmaf(v0, __int_as_float(p0.y), acc0);
        acc1 = fmaf(v1, __int_as_float(p1.y), acc1);
        acc2 = fmaf(v2, __int_as_float(p2.y), acc2);
        acc3 = fmaf(v3, __int_as_float(p3.y), acc3);
    }
    for (; j < end; ++j) {
        int2 p = packed[j];
        acc0 = fmaf(bf2f(h_in[(long long)p.x * D + lane]), __int_as_float(p.y), acc0);
    }
    float r = ((acc0 + acc1) + (acc2 + acc3)) * norm[node];
    h_out[(long long)node * D + lane] = __float2bfloat16(r);
}

// ---- gather layer 2 fused with mean: out = (h0_f32 + h1 + norm*sum h1[src]*coef)/3 ----
__global__ void gather2_final_kernel(const float* __restrict__ h0,
                                     const unsigned short* __restrict__ h1,
                                     const int2* __restrict__ packed, const int* __restrict__ rowptr,
                                     const float* __restrict__ norm, float* __restrict__ out, int N) {
    int node = blockIdx.x * (blockDim.x >> 6) + (threadIdx.x >> 6);
    int lane = threadIdx.x & 63;
    if (node >= N) return;
    int j = rowptr[node], end = rowptr[node + 1];
    float acc0 = 0.0f, acc1 = 0.0f, acc2 = 0.0f, acc3 = 0.0f;
    for (; j + 4 <= end; j += 4) {
        int2 p0 = packed[j], p1 = packed[j + 1], p2 = packed[j + 2], p3 = packed[j + 3];
        float v0 = bf2f(h1[(long long)p0.x * D + lane]);
        float v1 = bf2f(h1[(long long)p1.x * D + lane]);
        float v2 = bf2f(h1[(long long)p2.x * D + lane]);
        float v3 = bf2f(h1[(long long)p3.x * D + lane]);
        acc0 = fmaf(v0, __int_as_float(p0.y), acc0);
        acc1 = fmaf(v1, __int_as_float(p1.y), acc1);
        acc2 = fmaf(v2, __int_as_float(p2.y), acc2);
        acc3 = fmaf(v3, __int_as_float(p3.y), acc3);
    }
    for (; j < end; ++j) {
        int2 p = packed[j];
        acc0 = fmaf(bf2f(h1[(long long)p.x * D + lane]), __int_as_float(p.y), acc0);
    }
    long long idx = (long long)node * D + lane;
    float h2 = ((acc0 + acc1) + (acc2 + acc3)) * norm[node];
    out[idx] = (h0[idx] + bf2f(h1[idx]) + h2) * (1.0f / 3.0f);
}

extern "C" void kernel_launch(void* const* d_in, const int* in_sizes, int n_in,
                              void* d_out, int out_size, void* d_ws, size_t ws_size,
                              hipStream_t stream) {
    const float* h   = (const float*)d_in[0];
    const float* w   = (const float*)d_in[1];
    const int*   src = (const int*)d_in[2];
    const int*   dst = (const int*)d_in[3];
    const int N = in_sizes[0] / D;   // 100000
    const int E = in_sizes[1];       // 1600000
    float* out = (float*)d_out;

    // ---- workspace layout ----
    char* ws = (char*)d_ws;
    size_t off = 0;
    auto alloc = [&](size_t bytes, size_t align) -> char* {
        off = (off + align - 1) & ~(align - 1);
        char* p = ws + off;
        off += bytes;
        return p;
    };
    float* norm   = (float*)alloc((size_t)N * 4, 4);
    int*   rowptr = (int*)  alloc((size_t)(N + 1) * 4, 4);
    int*   partial= (int*)  alloc((size_t)1024 * 4, 4);
    int*   rank   = (int*)  alloc((size_t)E * 4, 4);
    int2*  packed = (int2*) alloc((size_t)E * 8, 8);
    // cntS (N*CSTRIDE ints, used only during CSR build) time-shares with h1bf
    char*  shared_region = alloc((size_t)N * CSTRIDE * 4, 128);   // 12.8 MB
    int*   cntS   = (int*)shared_region;
    __hip_bfloat16* h1bf = (__hip_bfloat16*)shared_region;        // N*D bf16 = 12.8 MB
    __hip_bfloat16* h0bf = (__hip_bfloat16*)alloc((size_t)N * D * 2, 128);

    const int eblocks = (E + THREADS - 1) / THREADS;
    const int nblocks = (N + THREADS - 1) / THREADS;
    const int P = (N + SCAN_BLOCK - 1) / SCAN_BLOCK;   // 391 <= 1024
    const int waves_per_block = THREADS / 64;
    const int gather_blocks = (N + waves_per_block - 1) / waves_per_block;
    const long long nd = (long long)N * D;
    const int cvt_blocks = (int)((nd + THREADS - 1) / THREADS);

    hipMemsetAsync(cntS, 0, (size_t)N * CSTRIDE * 4, stream);

    // CSR build: 1 atomic per edge, counters line-strided to avoid RMW serialization
    count_rank_kernel<<<eblocks, THREADS, 0, stream>>>(dst, cntS, rank, E);
    blocksum_kernel<<<P, SCAN_BLOCK, 0, stream>>>(cntS, partial, N);
    scanpartials_kernel<<<1, 1024, 0, stream>>>(partial, P, rowptr, N, E);
    rowptr_kernel<<<P, SCAN_BLOCK, 0, stream>>>(cntS, partial, rowptr, N);
    fill_kernel<<<eblocks, THREADS, 0, stream>>>(w, src, dst, rank, rowptr, packed, E);

    // norm from CSR, fold norm[src] into coefs, convert h to bf16
    degnorm_kernel<<<nblocks, THREADS, 0, stream>>>(packed, rowptr, norm, N);
    coef_kernel<<<eblocks, THREADS, 0, stream>>>(packed, norm, E);
    tobf16_kernel<<<cvt_blocks, THREADS, 0, stream>>>(h, h0bf, nd);

    // layer 1 (bf16 rows), layer 2 + mean epilogue
    gather1_kernel<<<gather_blocks, THREADS, 0, stream>>>((const unsigned short*)h0bf, packed,
                                                          rowptr, norm, h1bf, N);
    gather2_final_kernel<<<gather_blocks, THREADS, 0, stream>>>(h, (const unsigned short*)h1bf,
                                                                packed, rowptr, norm, out, N);
}

// Round 5
// 291.210 us; speedup vs baseline: 9.9523x; 1.2388x over previous
//
#include <hip/hip_runtime.h>
#include <hip/hip_bf16.h>

#define D 64
#define THREADS 256
#define SCAN_BLOCK 256
#define CSTRIDE 32   // one int counter per 128B cache line

// ---- bf16 helpers (bit tricks, RNE) ----
__device__ __forceinline__ unsigned f2bf(float f) {
    unsigned u = __float_as_uint(f);
    return (u + 0x7fffu + ((u >> 16) & 1u)) >> 16;
}
__device__ __forceinline__ float2 bfpair(unsigned v) {
    return make_float2(__uint_as_float(v << 16), __uint_as_float(v & 0xffff0000u));
}

// ---- pass 1: in-degree histogram (line-strided counters) + rank, 4 edges/thread ----
__global__ void count_rank_kernel(const int* __restrict__ dst, int* __restrict__ cntS,
                                  int* __restrict__ rank, int E) {
    int t = blockIdx.x * blockDim.x + threadIdx.x;
    int e = t * 4;
    if (e + 3 < E) {
        int4 d = *(const int4*)(dst + e);
        int4 r;
        r.x = atomicAdd(&cntS[(long long)d.x * CSTRIDE], 1);
        r.y = atomicAdd(&cntS[(long long)d.y * CSTRIDE], 1);
        r.z = atomicAdd(&cntS[(long long)d.z * CSTRIDE], 1);
        r.w = atomicAdd(&cntS[(long long)d.w * CSTRIDE], 1);
        *(int4*)(rank + e) = r;
    } else {
        for (; e < E; ++e) rank[e] = atomicAdd(&cntS[(long long)dst[e] * CSTRIDE], 1);
    }
}

// ---- scan step A: per-block sums of cnt ----
__global__ void blocksum_kernel(const int* __restrict__ cntS, int* __restrict__ partial, int N) {
    __shared__ int sm[SCAN_BLOCK];
    int i = blockIdx.x * SCAN_BLOCK + threadIdx.x;
    sm[threadIdx.x] = (i < N) ? cntS[(long long)i * CSTRIDE] : 0;
    __syncthreads();
    for (int s = SCAN_BLOCK / 2; s > 0; s >>= 1) {
        if (threadIdx.x < s) sm[threadIdx.x] += sm[threadIdx.x + s];
        __syncthreads();
    }
    if (threadIdx.x == 0) partial[blockIdx.x] = sm[0];
}

// ---- scan step B: exclusive scan of partials (single block, P <= 1024) ----
__global__ void scanpartials_kernel(int* __restrict__ partial, int P, int* __restrict__ rowptr,
                                    int N, int E) {
    __shared__ int sm[1024];
    int t = threadIdx.x;
    sm[t] = (t < P) ? partial[t] : 0;
    __syncthreads();
    for (int off = 1; off < 1024; off <<= 1) {
        int v = (t >= off) ? sm[t - off] : 0;
        __syncthreads();
        sm[t] += v;
        __syncthreads();
    }
    if (t < P) partial[t] = (t == 0) ? 0 : sm[t - 1];  // exclusive
    if (t == 0) rowptr[N] = E;
}

// ---- scan step C: rowptr[i] = partial[b] + exclusive_scan_within_block ----
__global__ void rowptr_kernel(const int* __restrict__ cntS, const int* __restrict__ partial,
                              int* __restrict__ rowptr, int N) {
    __shared__ int sm[SCAN_BLOCK];
    int i = blockIdx.x * SCAN_BLOCK + threadIdx.x;
    int v = (i < N) ? cntS[(long long)i * CSTRIDE] : 0;
    sm[threadIdx.x] = v;
    __syncthreads();
    for (int off = 1; off < SCAN_BLOCK; off <<= 1) {
        int u = (threadIdx.x >= off) ? sm[threadIdx.x - off] : 0;
        __syncthreads();
        sm[threadIdx.x] += u;
        __syncthreads();
    }
    if (i < N) rowptr[i] = partial[blockIdx.x] + (sm[threadIdx.x] - v);
}

// ---- fill: packed[rowptr[dst]+rank] = (src, w), 4 edges/thread, NO atomics ----
__global__ void fill_kernel(const float* __restrict__ w, const int* __restrict__ src,
                            const int* __restrict__ dst, const int* __restrict__ rank,
                            const int* __restrict__ rowptr, int2* __restrict__ packed, int E) {
    int t = blockIdx.x * blockDim.x + threadIdx.x;
    int e = t * 4;
    if (e + 3 < E) {
        int4 d = *(const int4*)(dst + e);
        int4 s = *(const int4*)(src + e);
        int4 r = *(const int4*)(rank + e);
        float4 wv = *(const float4*)(w + e);
        int b0 = rowptr[d.x], b1 = rowptr[d.y], b2 = rowptr[d.z], b3 = rowptr[d.w];
        packed[b0 + r.x] = make_int2(s.x, __float_as_int(wv.x));
        packed[b1 + r.y] = make_int2(s.y, __float_as_int(wv.y));
        packed[b2 + r.z] = make_int2(s.z, __float_as_int(wv.z));
        packed[b3 + r.w] = make_int2(s.w, __float_as_int(wv.w));
    } else {
        for (; e < E; ++e)
            packed[rowptr[dst[e]] + rank[e]] = make_int2(src[e], __float_as_int(w[e]));
    }
}

// ---- deg from CSR (segmented sum of w) fused with norm = rsqrt(max(deg,1)) ----
__global__ void degnorm_kernel(const int2* __restrict__ packed, const int* __restrict__ rowptr,
                               float* __restrict__ norm, int N) {
    int i = blockIdx.x * blockDim.x + threadIdx.x;
    if (i >= N) return;
    int j = rowptr[i], end = rowptr[i + 1];
    float s = 0.0f;
    for (; j < end; ++j) s += __int_as_float(packed[j].y);
    norm[i] = rsqrtf(fmaxf(s, 1.0f));
}

// ---- h (fp32) -> bf16, 4 elems/thread ----
__global__ void tobf16_kernel(const float* __restrict__ h, unsigned* __restrict__ hbf2,
                              long long nd4) {
    long long i = (long long)blockIdx.x * blockDim.x + threadIdx.x;
    if (i < nd4) {
        float4 v = ((const float4*)h)[i];
        ((uint2*)hbf2)[i] = make_uint2(f2bf(v.x) | (f2bf(v.y) << 16),
                                       f2bf(v.z) | (f2bf(v.w) << 16));
    }
}

// ---- gather layer 1: half-wave (32 lanes) per node, lane = 2 dims, unroll 4 ----
// h rows are 32 uints (64 bf16). coef = w * norm[src] computed inline.
__global__ void gather1_kernel(const unsigned* __restrict__ h_in, const int2* __restrict__ packed,
                               const int* __restrict__ rowptr, const float* __restrict__ norm,
                               unsigned* __restrict__ h_out, int N) {
    int node = blockIdx.x * (blockDim.x >> 5) + (threadIdx.x >> 5);
    int lane = threadIdx.x & 31;
    if (node >= N) return;
    int j = rowptr[node], end = rowptr[node + 1];
    float aL0 = 0, aH0 = 0, aL1 = 0, aH1 = 0, aL2 = 0, aH2 = 0, aL3 = 0, aH3 = 0;
    for (; j + 4 <= end; j += 4) {
        int2 p0 = packed[j], p1 = packed[j + 1], p2 = packed[j + 2], p3 = packed[j + 3];
        unsigned r0 = h_in[((long long)p0.x << 5) + lane];
        unsigned r1 = h_in[((long long)p1.x << 5) + lane];
        unsigned r2 = h_in[((long long)p2.x << 5) + lane];
        unsigned r3 = h_in[((long long)p3.x << 5) + lane];
        float c0 = __int_as_float(p0.y) * norm[p0.x];
        float c1 = __int_as_float(p1.y) * norm[p1.x];
        float c2 = __int_as_float(p2.y) * norm[p2.x];
        float c3 = __int_as_float(p3.y) * norm[p3.x];
        float2 f0 = bfpair(r0), f1 = bfpair(r1), f2 = bfpair(r2), f3 = bfpair(r3);
        aL0 = fmaf(f0.x, c0, aL0); aH0 = fmaf(f0.y, c0, aH0);
        aL1 = fmaf(f1.x, c1, aL1); aH1 = fmaf(f1.y, c1, aH1);
        aL2 = fmaf(f2.x, c2, aL2); aH2 = fmaf(f2.y, c2, aH2);
        aL3 = fmaf(f3.x, c3, aL3); aH3 = fmaf(f3.y, c3, aH3);
    }
    for (; j < end; ++j) {
        int2 p = packed[j];
        unsigned r = h_in[((long long)p.x << 5) + lane];
        float c = __int_as_float(p.y) * norm[p.x];
        float2 f = bfpair(r);
        aL0 = fmaf(f.x, c, aL0); aH0 = fmaf(f.y, c, aH0);
    }
    float nv = norm[node];
    float lo = ((aL0 + aL1) + (aL2 + aL3)) * nv;
    float hi = ((aH0 + aH1) + (aH2 + aH3)) * nv;
    h_out[((long long)node << 5) + lane] = f2bf(lo) | (f2bf(hi) << 16);
}

// ---- gather layer 2 + mean: out = (h0bf + h1bf + norm*sum h1[src]*coef)/3 ----
__global__ void gather2_final_kernel(const unsigned* __restrict__ h0bf,
                                     const unsigned* __restrict__ h1bf,
                                     const int2* __restrict__ packed, const int* __restrict__ rowptr,
                                     const float* __restrict__ norm, float* __restrict__ out, int N) {
    int node = blockIdx.x * (blockDim.x >> 5) + (threadIdx.x >> 5);
    int lane = threadIdx.x & 31;
    if (node >= N) return;
    int j = rowptr[node], end = rowptr[node + 1];
    float aL0 = 0, aH0 = 0, aL1 = 0, aH1 = 0, aL2 = 0, aH2 = 0, aL3 = 0, aH3 = 0;
    for (; j + 4 <= end; j += 4) {
        int2 p0 = packed[j], p1 = packed[j + 1], p2 = packed[j + 2], p3 = packed[j + 3];
        unsigned r0 = h1bf[((long long)p0.x << 5) + lane];
        unsigned r1 = h1bf[((long long)p1.x << 5) + lane];
        unsigned r2 = h1bf[((long long)p2.x << 5) + lane];
        unsigned r3 = h1bf[((long long)p3.x << 5) + lane];
        float c0 = __int_as_float(p0.y) * norm[p0.x];
        float c1 = __int_as_float(p1.y) * norm[p1.x];
        float c2 = __int_as_float(p2.y) * norm[p2.x];
        float c3 = __int_as_float(p3.y) * norm[p3.x];
        float2 f0 = bfpair(r0), f1 = bfpair(r1), f2 = bfpair(r2), f3 = bfpair(r3);
        aL0 = fmaf(f0.x, c0, aL0); aH0 = fmaf(f0.y, c0, aH0);
        aL1 = fmaf(f1.x, c1, aL1); aH1 = fmaf(f1.y, c1, aH1);
        aL2 = fmaf(f2.x, c2, aL2); aH2 = fmaf(f2.y, c2, aH2);
        aL3 = fmaf(f3.x, c3, aL3); aH3 = fmaf(f3.y, c3, aH3);
    }
    for (; j < end; ++j) {
        int2 p = packed[j];
        unsigned r = h1bf[((long long)p.x << 5) + lane];
        float c = __int_as_float(p.y) * norm[p.x];
        float2 f = bfpair(r);
        aL0 = fmaf(f.x, c, aL0); aH0 = fmaf(f.y, c, aH0);
    }
    long long idx = ((long long)node << 5) + lane;
    float nv = norm[node];
    float h2lo = ((aL0 + aL1) + (aL2 + aL3)) * nv;
    float h2hi = ((aH0 + aH1) + (aH2 + aH3)) * nv;
    float2 h0p = bfpair(h0bf[idx]);
    float2 h1p = bfpair(h1bf[idx]);
    float2 o;
    o.x = (h0p.x + h1p.x + h2lo) * (1.0f / 3.0f);
    o.y = (h0p.y + h1p.y + h2hi) * (1.0f / 3.0f);
    ((float2*)out)[idx] = o;
}

extern "C" void kernel_launch(void* const* d_in, const int* in_sizes, int n_in,
                              void* d_out, int out_size, void* d_ws, size_t ws_size,
                              hipStream_t stream) {
    const float* h   = (const float*)d_in[0];
    const float* w   = (const float*)d_in[1];
    const int*   src = (const int*)d_in[2];
    const int*   dst = (const int*)d_in[3];
    const int N = in_sizes[0] / D;   // 100000
    const int E = in_sizes[1];       // 1600000
    float* out = (float*)d_out;

    // ---- workspace layout ----
    char* ws = (char*)d_ws;
    size_t off = 0;
    auto alloc = [&](size_t bytes, size_t align) -> char* {
        off = (off + align - 1) & ~(align - 1);
        char* p = ws + off;
        off += bytes;
        return p;
    };
    float* norm   = (float*)alloc((size_t)N * 4, 16);
    int*   rowptr = (int*)  alloc((size_t)(N + 1) * 4, 16);
    int*   partial= (int*)  alloc((size_t)1024 * 4, 16);
    int*   rank   = (int*)  alloc((size_t)E * 4, 16);
    int2*  packed = (int2*) alloc((size_t)E * 8, 16);
    // cntS (build phase) time-shares with h1bf (gather phase)
    char*  shared_region = alloc((size_t)N * CSTRIDE * 4, 128);   // 12.8 MB
    int*      cntS = (int*)shared_region;
    unsigned* h1bf = (unsigned*)shared_region;                    // N*32 uints = 12.8 MB
    unsigned* h0bf = (unsigned*)alloc((size_t)N * D * 2, 128);

    const int e4blocks = (E / 4 + THREADS - 1) / THREADS;
    const int nblocks = (N + THREADS - 1) / THREADS;
    const int P = (N + SCAN_BLOCK - 1) / SCAN_BLOCK;   // 391 <= 1024
    const int nodes_per_block = THREADS / 32;          // half-wave per node
    const int gather_blocks = (N + nodes_per_block - 1) / nodes_per_block;
    const long long nd4 = (long long)N * D / 4;
    const int cvt_blocks = (int)((nd4 + THREADS - 1) / THREADS);

    hipMemsetAsync(cntS, 0, (size_t)N * CSTRIDE * 4, stream);

    // CSR build: 1 atomic per edge, line-strided counters, x4 batched
    count_rank_kernel<<<e4blocks, THREADS, 0, stream>>>(dst, cntS, rank, E);
    blocksum_kernel<<<P, SCAN_BLOCK, 0, stream>>>(cntS, partial, N);
    scanpartials_kernel<<<1, 1024, 0, stream>>>(partial, P, rowptr, N, E);
    rowptr_kernel<<<P, SCAN_BLOCK, 0, stream>>>(cntS, partial, rowptr, N);
    fill_kernel<<<e4blocks, THREADS, 0, stream>>>(w, src, dst, rank, rowptr, packed, E);

    // norm from CSR; h -> bf16
    degnorm_kernel<<<nblocks, THREADS, 0, stream>>>(packed, rowptr, norm, N);
    tobf16_kernel<<<cvt_blocks, THREADS, 0, stream>>>(h, h0bf, nd4);

    // gathers: norm[src] folded in on the fly (group-uniform load)
    gather1_kernel<<<gather_blocks, THREADS, 0, stream>>>(h0bf, packed, rowptr, norm, h1bf, N);
    gather2_final_kernel<<<gather_blocks, THREADS, 0, stream>>>(h0bf, h1bf, packed, rowptr,
                                                                norm, out, N);
}

// Round 6
// 234.273 us; speedup vs baseline: 12.3710x; 1.2430x over previous
//
#include <hip/hip_runtime.h>
#include <hip/hip_bf16.h>

#define D 64
#define THREADS 256
#define BKT_BITS 9                 // 512 nodes per bucket
#define BKT_NODES (1 << BKT_BITS)
#define CHUNK 8192                 // edges per pass-1 block

// ---- bf16 helpers (bit tricks, RNE) ----
__device__ __forceinline__ unsigned f2bf(float f) {
    unsigned u = __float_as_uint(f);
    return (u + 0x7fffu + ((u >> 16) & 1u)) >> 16;
}
__device__ __forceinline__ float2 bfpair(unsigned v) {
    return make_float2(__uint_as_float(v << 16), __uint_as_float(v & 0xffff0000u));
}

// ---- p1a: per-chunk LDS histogram of coarse buckets (B <= 256) ----
__global__ void p1a_hist(const int* __restrict__ dst, int* __restrict__ blockCount,
                         int E, int B) {
    __shared__ int lc[256];
    int t = threadIdx.x;
    lc[t] = 0;
    __syncthreads();
    int base = blockIdx.x * CHUNK;
    int end = min(base + CHUNK, E);
    for (int e = base + t; e < end; e += THREADS)
        atomicAdd(&lc[dst[e] >> BKT_BITS], 1);
    __syncthreads();
    if (t < B) blockCount[(long long)blockIdx.x * B + t] = lc[t];
}

// ---- p1b: per-bucket exclusive scan over blocks (in place) + bucket totals ----
__global__ void p1b_scanblocks(int* __restrict__ blockCount, int* __restrict__ total,
                               int NBLK, int B) {
    __shared__ int sm[256];
    int b = blockIdx.x, t = threadIdx.x;
    int run = 0;
    for (int base = 0; base < NBLK; base += 256) {
        int i = base + t;
        int v = (i < NBLK) ? blockCount[(long long)i * B + b] : 0;
        sm[t] = v;
        __syncthreads();
        for (int off = 1; off < 256; off <<= 1) {
            int u = (t >= off) ? sm[t - off] : 0;
            __syncthreads();
            sm[t] += u;
            __syncthreads();
        }
        if (i < NBLK) blockCount[(long long)i * B + b] = run + sm[t] - v;
        run += sm[255];
        __syncthreads();
    }
    if (t == 0) total[b] = run;
}

// ---- p1c: exclusive scan of bucket totals -> bstart[B+1] ----
__global__ void p1c_scanbuckets(const int* __restrict__ total, int* __restrict__ bstart,
                                int B, int E) {
    __shared__ int sm[256];
    int t = threadIdx.x;
    int run = 0;
    for (int base = 0; base < B; base += 256) {
        int i = base + t;
        int v = (i < B) ? total[i] : 0;
        sm[t] = v;
        __syncthreads();
        for (int off = 1; off < 256; off <<= 1) {
            int u = (t >= off) ? sm[t - off] : 0;
            __syncthreads();
            sm[t] += u;
            __syncthreads();
        }
        if (i < B) bstart[i] = run + sm[t] - v;
        run += sm[255];
        __syncthreads();
    }
    if (t == 0) bstart[B] = E;
}

// ---- p1d: scatter edges into bucket-partitioned temp via LDS cursors ----
// temp[pos] = (src | dstlow<<17, w)   [src < 2^17 since N=100k]
__global__ void p1d_scatter(const int* __restrict__ dst, const int* __restrict__ src,
                            const float* __restrict__ w, const int* __restrict__ blockCount,
                            const int* __restrict__ bstart, int2* __restrict__ temp,
                            int E, int B) {
    __shared__ int cur[256];
    int t = threadIdx.x;
    if (t < B) cur[t] = bstart[t] + blockCount[(long long)blockIdx.x * B + t];
    __syncthreads();
    int base = blockIdx.x * CHUNK;
    int end = min(base + CHUNK, E);
    for (int e = base + t; e < end; e += THREADS) {
        int d = dst[e];
        int b = d >> BKT_BITS;
        int pos = atomicAdd(&cur[b], 1);                       // LDS atomic w/ return
        temp[pos] = make_int2(src[e] | ((d & (BKT_NODES - 1)) << 17),
                              __float_as_int(w[e]));
    }
}

// ---- p2: per-bucket CSR finalize: histogram+deg (LDS) -> scan -> rowptr/norm/packed ----
__global__ void p2_build(const int2* __restrict__ temp, const int* __restrict__ bstart,
                         int2* __restrict__ packed, int* __restrict__ rowptr,
                         float* __restrict__ norm, int N, int E, int B) {
    __shared__ int cnt[BKT_NODES];
    __shared__ float degs[BKT_NODES];
    __shared__ int cur[BKT_NODES];
    __shared__ int sm[256];
    int b = blockIdx.x, t = threadIdx.x;
    int ebeg = bstart[b], eend = bstart[b + 1];
    for (int i = t; i < BKT_NODES; i += THREADS) { cnt[i] = 0; degs[i] = 0.0f; }
    __syncthreads();
    for (int e = ebeg + t; e < eend; e += THREADS) {
        int2 pk = temp[e];
        int dl = (pk.x >> 17) & (BKT_NODES - 1);
        atomicAdd(&cnt[dl], 1);
        atomicAdd(&degs[dl], __int_as_float(pk.y));
    }
    __syncthreads();
    // block exclusive scan of cnt[512] -> cur[512]
    int run = 0;
    for (int base = 0; base < BKT_NODES; base += 256) {
        int v = cnt[base + t];
        sm[t] = v;
        __syncthreads();
        for (int off = 1; off < 256; off <<= 1) {
            int u = (t >= off) ? sm[t - off] : 0;
            __syncthreads();
            sm[t] += u;
            __syncthreads();
        }
        cur[base + t] = run + sm[t] - v;
        run += sm[255];
        __syncthreads();
    }
    // rowptr + norm
    int node0 = b << BKT_BITS;
    for (int i = t; i < BKT_NODES; i += THREADS) {
        int node = node0 + i;
        if (node < N) {
            rowptr[node] = ebeg + cur[i];
            norm[node] = rsqrtf(fmaxf(degs[i], 1.0f));
        }
    }
    if (b == 0 && t == 0) rowptr[N] = E;
    __syncthreads();
    // placement: packed[ebeg + pos] = (src, w)
    for (int e = ebeg + t; e < eend; e += THREADS) {
        int2 pk = temp[e];
        int dl = (pk.x >> 17) & (BKT_NODES - 1);
        int pos = atomicAdd(&cur[dl], 1);                      // LDS atomic w/ return
        packed[ebeg + pos] = make_int2(pk.x & 0x1ffff, pk.y);
    }
}

// ---- h (fp32) -> bf16 packed pairs, 4 elems/thread ----
__global__ void tobf16_kernel(const float* __restrict__ h, unsigned* __restrict__ hbf2,
                              long long nd4) {
    long long i = (long long)blockIdx.x * blockDim.x + threadIdx.x;
    if (i < nd4) {
        float4 v = ((const float4*)h)[i];
        ((uint2*)hbf2)[i] = make_uint2(f2bf(v.x) | (f2bf(v.y) << 16),
                                       f2bf(v.z) | (f2bf(v.w) << 16));
    }
}

// ---- gather layer 1: quarter-wave (16 lanes) per node, lane = 4 dims, unroll 4 ----
__global__ void gather1_kernel(const uint2* __restrict__ h_in, const int2* __restrict__ packed,
                               const int* __restrict__ rowptr, const float* __restrict__ norm,
                               uint2* __restrict__ h_out, int N) {
    int node = blockIdx.x * (blockDim.x >> 4) + (threadIdx.x >> 4);
    int lane = threadIdx.x & 15;
    if (node >= N) return;
    int j = rowptr[node], end = rowptr[node + 1];
    float a00 = 0, a01 = 0, a02 = 0, a03 = 0;
    float a10 = 0, a11 = 0, a12 = 0, a13 = 0;
    float a20 = 0, a21 = 0, a22 = 0, a23 = 0;
    float a30 = 0, a31 = 0, a32 = 0, a33 = 0;
    for (; j + 4 <= end; j += 4) {
        int2 p0 = packed[j], p1 = packed[j + 1], p2 = packed[j + 2], p3 = packed[j + 3];
        uint2 r0 = h_in[((long long)p0.x << 4) + lane];
        uint2 r1 = h_in[((long long)p1.x << 4) + lane];
        uint2 r2 = h_in[((long long)p2.x << 4) + lane];
        uint2 r3 = h_in[((long long)p3.x << 4) + lane];
        float c0 = __int_as_float(p0.y) * norm[p0.x];
        float c1 = __int_as_float(p1.y) * norm[p1.x];
        float c2 = __int_as_float(p2.y) * norm[p2.x];
        float c3 = __int_as_float(p3.y) * norm[p3.x];
        float2 f0a = bfpair(r0.x), f0b = bfpair(r0.y);
        float2 f1a = bfpair(r1.x), f1b = bfpair(r1.y);
        float2 f2a = bfpair(r2.x), f2b = bfpair(r2.y);
        float2 f3a = bfpair(r3.x), f3b = bfpair(r3.y);
        a00 = fmaf(f0a.x, c0, a00); a01 = fmaf(f0a.y, c0, a01);
        a02 = fmaf(f0b.x, c0, a02); a03 = fmaf(f0b.y, c0, a03);
        a10 = fmaf(f1a.x, c1, a10); a11 = fmaf(f1a.y, c1, a11);
        a12 = fmaf(f1b.x, c1, a12); a13 = fmaf(f1b.y, c1, a13);
        a20 = fmaf(f2a.x, c2, a20); a21 = fmaf(f2a.y, c2, a21);
        a22 = fmaf(f2b.x, c2, a22); a23 = fmaf(f2b.y, c2, a23);
        a30 = fmaf(f3a.x, c3, a30); a31 = fmaf(f3a.y, c3, a31);
        a32 = fmaf(f3b.x, c3, a32); a33 = fmaf(f3b.y, c3, a33);
    }
    for (; j < end; ++j) {
        int2 p = packed[j];
        uint2 r = h_in[((long long)p.x << 4) + lane];
        float c = __int_as_float(p.y) * norm[p.x];
        float2 fa = bfpair(r.x), fb = bfpair(r.y);
        a00 = fmaf(fa.x, c, a00); a01 = fmaf(fa.y, c, a01);
        a02 = fmaf(fb.x, c, a02); a03 = fmaf(fb.y, c, a03);
    }
    float nv = norm[node];
    float d0 = ((a00 + a10) + (a20 + a30)) * nv;
    float d1 = ((a01 + a11) + (a21 + a31)) * nv;
    float d2 = ((a02 + a12) + (a22 + a32)) * nv;
    float d3 = ((a03 + a13) + (a23 + a33)) * nv;
    h_out[((long long)node << 4) + lane] =
        make_uint2(f2bf(d0) | (f2bf(d1) << 16), f2bf(d2) | (f2bf(d3) << 16));
}

// ---- gather layer 2 + mean: out = (h0 + h1 + norm*sum h1[src]*coef)/3 ----
__global__ void gather2_final_kernel(const uint2* __restrict__ h0bf, const uint2* __restrict__ h1bf,
                                     const int2* __restrict__ packed, const int* __restrict__ rowptr,
                                     const float* __restrict__ norm, float* __restrict__ out, int N) {
    int node = blockIdx.x * (blockDim.x >> 4) + (threadIdx.x >> 4);
    int lane = threadIdx.x & 15;
    if (node >= N) return;
    int j = rowptr[node], end = rowptr[node + 1];
    float a00 = 0, a01 = 0, a02 = 0, a03 = 0;
    float a10 = 0, a11 = 0, a12 = 0, a13 = 0;
    float a20 = 0, a21 = 0, a22 = 0, a23 = 0;
    float a30 = 0, a31 = 0, a32 = 0, a33 = 0;
    for (; j + 4 <= end; j += 4) {
        int2 p0 = packed[j], p1 = packed[j + 1], p2 = packed[j + 2], p3 = packed[j + 3];
        uint2 r0 = h1bf[((long long)p0.x << 4) + lane];
        uint2 r1 = h1bf[((long long)p1.x << 4) + lane];
        uint2 r2 = h1bf[((long long)p2.x << 4) + lane];
        uint2 r3 = h1bf[((long long)p3.x << 4) + lane];
        float c0 = __int_as_float(p0.y) * norm[p0.x];
        float c1 = __int_as_float(p1.y) * norm[p1.x];
        float c2 = __int_as_float(p2.y) * norm[p2.x];
        float c3 = __int_as_float(p3.y) * norm[p3.x];
        float2 f0a = bfpair(r0.x), f0b = bfpair(r0.y);
        float2 f1a = bfpair(r1.x), f1b = bfpair(r1.y);
        float2 f2a = bfpair(r2.x), f2b = bfpair(r2.y);
        float2 f3a = bfpair(r3.x), f3b = bfpair(r3.y);
        a00 = fmaf(f0a.x, c0, a00); a01 = fmaf(f0a.y, c0, a01);
        a02 = fmaf(f0b.x, c0, a02); a03 = fmaf(f0b.y, c0, a03);
        a10 = fmaf(f1a.x, c1, a10); a11 = fmaf(f1a.y, c1, a11);
        a12 = fmaf(f1b.x, c1, a12); a13 = fmaf(f1b.y, c1, a13);
        a20 = fmaf(f2a.x, c2, a20); a21 = fmaf(f2a.y, c2, a21);
        a22 = fmaf(f2b.x, c2, a22); a23 = fmaf(f2b.y, c2, a23);
        a30 = fmaf(f3a.x, c3, a30); a31 = fmaf(f3a.y, c3, a31);
        a32 = fmaf(f3b.x, c3, a32); a33 = fmaf(f3b.y, c3, a33);
    }
    for (; j < end; ++j) {
        int2 p = packed[j];
        uint2 r = h1bf[((long long)p.x << 4) + lane];
        float c = __int_as_float(p.y) * norm[p.x];
        float2 fa = bfpair(r.x), fb = bfpair(r.y);
        a00 = fmaf(fa.x, c, a00); a01 = fmaf(fa.y, c, a01);
        a02 = fmaf(fb.x, c, a02); a03 = fmaf(fb.y, c, a03);
    }
    long long idx = ((long long)node << 4) + lane;
    float nv = norm[node];
    uint2 h0r = h0bf[idx], h1r = h1bf[idx];
    float2 h0a = bfpair(h0r.x), h0b = bfpair(h0r.y);
    float2 h1a = bfpair(h1r.x), h1b = bfpair(h1r.y);
    float4 o;
    o.x = (h0a.x + h1a.x + ((a00 + a10) + (a20 + a30)) * nv) * (1.0f / 3.0f);
    o.y = (h0a.y + h1a.y + ((a01 + a11) + (a21 + a31)) * nv) * (1.0f / 3.0f);
    o.z = (h0b.x + h1b.x + ((a02 + a12) + (a22 + a32)) * nv) * (1.0f / 3.0f);
    o.w = (h0b.y + h1b.y + ((a03 + a13) + (a23 + a33)) * nv) * (1.0f / 3.0f);
    ((float4*)out)[idx] = o;
}

extern "C" void kernel_launch(void* const* d_in, const int* in_sizes, int n_in,
                              void* d_out, int out_size, void* d_ws, size_t ws_size,
                              hipStream_t stream) {
    const float* h   = (const float*)d_in[0];
    const float* w   = (const float*)d_in[1];
    const int*   src = (const int*)d_in[2];
    const int*   dst = (const int*)d_in[3];
    const int N = in_sizes[0] / D;   // 100000
    const int E = in_sizes[1];       // 1600000
    float* out = (float*)d_out;

    const int B = (N + BKT_NODES - 1) >> BKT_BITS;   // 196 (<= 256 required)
    const int NBLK = (E + CHUNK - 1) / CHUNK;        // 196

    // ---- workspace layout ----
    char* ws = (char*)d_ws;
    size_t off = 0;
    auto alloc = [&](size_t bytes, size_t align) -> char* {
        off = (off + align - 1) & ~(align - 1);
        char* p = ws + off;
        off += bytes;
        return p;
    };
    float* norm     = (float*)alloc((size_t)N * 4, 16);
    int*   rowptr   = (int*)  alloc((size_t)(N + 1) * 4, 16);
    int*   total    = (int*)  alloc((size_t)B * 4, 16);
    int*   bstart   = (int*)  alloc((size_t)(B + 1) * 4, 16);
    int*   blockCnt = (int*)  alloc((size_t)NBLK * B * 4, 16);
    int2*  packed   = (int2*) alloc((size_t)E * 8, 16);
    // temp (build phase) time-shares with h1bf (gather phase), both 12.8 MB
    char*  shared_region = alloc((size_t)E * 8, 128);
    int2*     temp = (int2*)shared_region;
    unsigned* h1bf = (unsigned*)shared_region;
    unsigned* h0bf = (unsigned*)alloc((size_t)N * D * 2, 128);

    const int nodes_per_block = THREADS / 16;        // quarter-wave per node
    const int gather_blocks = (N + nodes_per_block - 1) / nodes_per_block;
    const long long nd4 = (long long)N * D / 4;
    const int cvt_blocks = (int)((nd4 + THREADS - 1) / THREADS);

    // CSR build: zero global atomics (LDS counting sort, 2 passes)
    p1a_hist<<<NBLK, THREADS, 0, stream>>>(dst, blockCnt, E, B);
    p1b_scanblocks<<<B, 256, 0, stream>>>(blockCnt, total, NBLK, B);
    p1c_scanbuckets<<<1, 256, 0, stream>>>(total, bstart, B, E);
    p1d_scatter<<<NBLK, THREADS, 0, stream>>>(dst, src, w, blockCnt, bstart, temp, E, B);
    p2_build<<<B, 256, 0, stream>>>(temp, bstart, packed, rowptr, norm, N, E, B);

    // h -> bf16
    tobf16_kernel<<<cvt_blocks, THREADS, 0, stream>>>(h, h0bf, nd4);

    // gathers (norm[src] folded inline; quarter-wave, 16 rows in flight per wave)
    gather1_kernel<<<gather_blocks, THREADS, 0, stream>>>((const uint2*)h0bf, packed, rowptr,
                                                          norm, (uint2*)h1bf, N);
    gather2_final_kernel<<<gather_blocks, THREADS, 0, stream>>>((const uint2*)h0bf, (const uint2*)h1bf,
                                                                packed, rowptr, norm, out, N);
}